// Round 8
// baseline (235.140 us; speedup 1.0000x reference)
//
#include <hip/hip_runtime.h>
#include <hip/hip_bf16.h>

// N=50000, E=600000, D=128, R=500 — fp32 inputs, bf16-tolerant check (thr 0.535).
// out = relu( (gather_sum(h[src]+emb[etype]) * norm) @ Wn + h @ (deg>0 ? Wl : We) )
// R8: revert R7's LDS-gather regression (emb was already L2-cheap; LDS cost
// 50 MB staging + halved occupancy). New: block-role-split kernel runs the
// gather CONCURRENTLY with P1 = h@Wl (independent of gather), P1 stored as
// bf16 C-frags; P2 = aggn@Wn + P1 + relu + deg==0 fixup. Hides ~12 us of
// GEMM under the 43 us gather (gather is at its random-line L3 ceiling:
// R6 2x-MLP neutral, R7 occupancy/LDS hurt).

#define DIM 128

typedef __attribute__((ext_vector_type(8))) short bf16x8_t;
typedef __attribute__((ext_vector_type(4))) float f32x4_t;

__device__ inline ushort f2bf(float f) {
    __hip_bfloat16 b = __float2bfloat16(f);
    return *reinterpret_cast<ushort*>(&b);
}
__device__ inline float bf2f(ushort u) {
    unsigned v = ((unsigned)u) << 16;
    return __uint_as_float(v);
}
__device__ inline uint4 cvt8(const float4& a, const float4& b) {
    uint4 o;
    o.x = f2bf(a.x) | ((unsigned)f2bf(a.y) << 16);
    o.y = f2bf(a.z) | ((unsigned)f2bf(a.w) << 16);
    o.z = f2bf(b.x) | ((unsigned)f2bf(b.y) << 16);
    o.w = f2bf(b.z) | ((unsigned)f2bf(b.w) << 16);
    return o;
}

// ---------- k1: fused init ------------------------------------------------
// ranges: [0,nH8) h conv | [+nE8) emb conv | +32768 Bpack | +N head=-1
__global__ __launch_bounds__(256) void init_kernel(
    const float4* __restrict__ h4, const float4* __restrict__ emb4,
    const float* __restrict__ Wn, const float* __restrict__ Wl,
    uint4* __restrict__ h8, uint4* __restrict__ emb8,
    ushort* __restrict__ Bpack, int* __restrict__ head,
    int nH8, int nE8, int N)
{
    int i = blockIdx.x * 256 + threadIdx.x;
    if (i < nH8) {
        h8[i] = cvt8(h4[2 * i], h4[2 * i + 1]);
        return;
    }
    int j = i - nH8;
    if (j < nE8) {
        emb8[j] = cvt8(emb4[2 * j], emb4[2 * j + 1]);
        return;
    }
    j -= nE8;
    if (j < 32768) {
        // Bpack[(((nt8*8+ks8)*64+lane)*8+jj)] = W[ks8*32+(lane>>4)*8+jj][nt8*16+(lane&15)]
        // ks8 0..3 -> Wn rows 0..127; ks8 4..7 -> Wl rows 0..127. nt8 0..7 -> all 128 cols.
        int jj   = j & 7;
        int lane = (j >> 3) & 63;
        int ks   = (j >> 9) & 7;
        int nt   = j >> 12;
        int k = ks * 32 + (lane >> 4) * 8 + jj;
        int n = nt * 16 + (lane & 15);
        float v = (k < DIM) ? Wn[k * DIM + n] : Wl[(k - DIM) * DIM + n];
        Bpack[j] = f2bf(v);
        return;
    }
    j -= 32768;
    if (j < N) head[j] = -1;
}

// ---------- k2: one-pass linked-list bucketing ----------------------------
// list[e] = { src|etype<<17, prev head }; head[dst] = e.
__global__ __launch_bounds__(256) void build_kernel(
    const int4* __restrict__ src4, const int4* __restrict__ dst4,
    const int4* __restrict__ et4, int* __restrict__ head,
    uint2* __restrict__ list, int E4,
    const int* __restrict__ src, const int* __restrict__ dst,
    const int* __restrict__ etype, int E)
{
    int i = blockIdx.x * 256 + threadIdx.x;
    if (i < E4) {
        int4 s = src4[i], d = dst4[i], t = et4[i];
        int e = 4 * i;
        int old;
        old = atomicExch(head + d.x, e + 0);
        list[e + 0] = make_uint2((unsigned)s.x | ((unsigned)t.x << 17), (unsigned)old);
        old = atomicExch(head + d.y, e + 1);
        list[e + 1] = make_uint2((unsigned)s.y | ((unsigned)t.y << 17), (unsigned)old);
        old = atomicExch(head + d.z, e + 2);
        list[e + 2] = make_uint2((unsigned)s.z | ((unsigned)t.z << 17), (unsigned)old);
        old = atomicExch(head + d.w, e + 3);
        list[e + 3] = make_uint2((unsigned)s.w | ((unsigned)t.w << 17), (unsigned)old);
    }
    if (i == 0)
        for (int e = E4 * 4; e < E; ++e) {
            int old = atomicExch(head + dst[e], e);
            list[e] = make_uint2((unsigned)src[e] | ((unsigned)etype[e] << 17),
                                 (unsigned)old);
        }
}

// ---------- k3: gather (role A) || P1 = h@Wl (role B) ----------------------
__device__ inline void addbf8(float* a, uint4 hv, uint4 rv) {
    a[0] += bf2f((ushort)(hv.x & 0xFFFF)) + bf2f((ushort)(rv.x & 0xFFFF));
    a[1] += bf2f((ushort)(hv.x >> 16))    + bf2f((ushort)(rv.x >> 16));
    a[2] += bf2f((ushort)(hv.y & 0xFFFF)) + bf2f((ushort)(rv.y & 0xFFFF));
    a[3] += bf2f((ushort)(hv.y >> 16))    + bf2f((ushort)(rv.y >> 16));
    a[4] += bf2f((ushort)(hv.z & 0xFFFF)) + bf2f((ushort)(rv.z & 0xFFFF));
    a[5] += bf2f((ushort)(hv.z >> 16))    + bf2f((ushort)(rv.z >> 16));
    a[6] += bf2f((ushort)(hv.w & 0xFFFF)) + bf2f((ushort)(rv.w & 0xFFFF));
    a[7] += bf2f((ushort)(hv.w >> 16))    + bf2f((ushort)(rv.w >> 16));
}
__device__ inline void store8(uint4* aggn8, int n, int lane, const float* a, float nm) {
    uint4 o;
    o.x = f2bf(a[0] * nm) | ((unsigned)f2bf(a[1] * nm) << 16);
    o.y = f2bf(a[2] * nm) | ((unsigned)f2bf(a[3] * nm) << 16);
    o.z = f2bf(a[4] * nm) | ((unsigned)f2bf(a[5] * nm) << 16);
    o.w = f2bf(a[6] * nm) | ((unsigned)f2bf(a[7] * nm) << 16);
    aggn8[(size_t)n * 16 + lane] = o;
}

__global__ __launch_bounds__(256) void gather_p1_kernel(
    const uint4* __restrict__ h8,      // [N][16] bf16
    const uint4* __restrict__ emb8,    // [R][16] bf16
    const float* __restrict__ norm,
    const int* __restrict__ head,
    const uint2* __restrict__ list,
    uint4* __restrict__ aggn8,         // [N][16] bf16 (out, role A)
    const ushort* __restrict__ h_bf,   // [N][128]
    const ushort* __restrict__ Bpack,
    ushort* __restrict__ P1f,          // [nRowTiles][64][32] bf16 C-frags (out, role B)
    int N, int gatherBlocks, int nRowTiles, int p1Waves)
{
    if ((int)blockIdx.x < gatherBlocks) {
        // ---- role A: gather, 2 interleaved chains per 16-lane group ----
        int g = blockIdx.x * 16 + (threadIdx.x >> 4);
        int lane = threadIdx.x & 15;
        int n0 = 2 * g;
        int n1 = 2 * g + 1;
        if (n0 >= N) return;
        bool has1 = (n1 < N);
        int c0 = head[n0];
        int c1 = has1 ? head[n1] : -1;

        float a0[8] = {0.f, 0.f, 0.f, 0.f, 0.f, 0.f, 0.f, 0.f};
        float a1[8] = {0.f, 0.f, 0.f, 0.f, 0.f, 0.f, 0.f, 0.f};

        while ((c0 >= 0) || (c1 >= 0)) {
            bool d0 = (c0 >= 0), d1 = (c1 >= 0);
            uint2 v0, v1;
            uint4 hv0, rv0, hv1, rv1;
            if (d0) v0 = list[c0];
            if (d1) v1 = list[c1];
            if (d0) {
                hv0 = h8[(size_t)(v0.x & 0x1FFFF) * 16 + lane];
                rv0 = emb8[(size_t)(v0.x >> 17) * 16 + lane];
            }
            if (d1) {
                hv1 = h8[(size_t)(v1.x & 0x1FFFF) * 16 + lane];
                rv1 = emb8[(size_t)(v1.x >> 17) * 16 + lane];
            }
            if (d0) { addbf8(a0, hv0, rv0); c0 = (int)v0.y; }
            if (d1) { addbf8(a1, hv1, rv1); c1 = (int)v1.y; }
        }
        store8(aggn8, n0, lane, a0, norm[n0]);
        if (has1) store8(aggn8, n1, lane, a1, norm[n1]);
        return;
    }

    // ---- role B: P1 = h_bf @ Wl, all 128 cols per wave, b reloaded per nt
    int wave = threadIdx.x >> 6;
    int lane = threadIdx.x & 63;
    int m    = lane & 15;
    int quad = lane >> 4;
    int pw   = ((int)blockIdx.x - gatherBlocks) * 4 + wave;

    for (int rt = pw; rt < nRowTiles; rt += p1Waves) {
        size_t rowOff = (size_t)(rt * 16 + m) * DIM + quad * 8;
        bf16x8_t a[4];
        #pragma unroll
        for (int ks = 0; ks < 4; ++ks)
            a[ks] = *(const bf16x8_t*)(h_bf + rowOff + ks * 32);

        uint2 o[8];
        #pragma unroll
        for (int nt = 0; nt < 8; ++nt) {
            f32x4_t acc;
            acc[0] = 0.f; acc[1] = 0.f; acc[2] = 0.f; acc[3] = 0.f;
            #pragma unroll
            for (int ks = 0; ks < 4; ++ks) {
                bf16x8_t b = *(const bf16x8_t*)(Bpack +
                    (((size_t)nt * 8 + ks + 4) * 64 + lane) * 8);   // Wl: ks8=4..7
                acc = __builtin_amdgcn_mfma_f32_16x16x32_bf16(a[ks], b, acc, 0, 0, 0);
            }
            o[nt].x = (unsigned)f2bf(acc[0]) | ((unsigned)f2bf(acc[1]) << 16);
            o[nt].y = (unsigned)f2bf(acc[2]) | ((unsigned)f2bf(acc[3]) << 16);
        }
        uint4* dst = (uint4*)(P1f + ((size_t)rt * 64 + lane) * 32);
        dst[0] = make_uint4(o[0].x, o[0].y, o[1].x, o[1].y);
        dst[1] = make_uint4(o[2].x, o[2].y, o[3].x, o[3].y);
        dst[2] = make_uint4(o[4].x, o[4].y, o[5].x, o[5].y);
        dst[3] = make_uint4(o[6].x, o[6].y, o[7].x, o[7].y);
    }
}

// ---------- k4: P2 = aggn@Wn + P1 + relu (+ deg==0 fixup) ------------------
// Persistent B (Wn half, ch-split: 64 cols/wave), streams aggn a-frags,
// adds P1 frags (lane-aligned C layout), relu, scattered store.
__global__ __launch_bounds__(256) void p2_kernel(
    const ushort* __restrict__ aggn_bf,  // [N][128]
    const ushort* __restrict__ Bpack,
    const ushort* __restrict__ P1f,      // [nRowTiles][64][32]
    const int* __restrict__ head,        // [N]
    const float* __restrict__ hf,        // [N][128] fp32
    const float* __restrict__ We,        // [128][128] fp32
    float* __restrict__ out,             // [N][128]
    int nRowTiles, int halfWaves)
{
    int wave = threadIdx.x >> 6;
    int lane = threadIdx.x & 63;
    int wid  = blockIdx.x * 4 + wave;
    int ch   = wid & 1;                  // column half
    int w    = wid >> 1;
    int m    = lane & 15;
    int quad = lane >> 4;

    bf16x8_t b[4][4];                    // Wn: ks8 = 0..3, nt8 = ch*4..ch*4+3
    #pragma unroll
    for (int nt = 0; nt < 4; ++nt)
        #pragma unroll
        for (int ks = 0; ks < 4; ++ks)
            b[nt][ks] = *(const bf16x8_t*)(Bpack +
                (((size_t)(ch * 4 + nt) * 8 + ks) * 64 + lane) * 8);

    for (int rt = w; rt < nRowTiles; rt += halfWaves) {
        size_t rowOff = (size_t)(rt * 16 + m) * DIM + quad * 8;
        bf16x8_t a[4];
        #pragma unroll
        for (int ks = 0; ks < 4; ++ks)
            a[ks] = *(const bf16x8_t*)(aggn_bf + rowOff + ks * 32);

        f32x4_t acc[4];
        #pragma unroll
        for (int nt = 0; nt < 4; ++nt) {
            acc[nt][0] = 0.f; acc[nt][1] = 0.f; acc[nt][2] = 0.f; acc[nt][3] = 0.f;
        }
        #pragma unroll
        for (int ks = 0; ks < 4; ++ks)
            #pragma unroll
            for (int nt = 0; nt < 4; ++nt)
                acc[nt] = __builtin_amdgcn_mfma_f32_16x16x32_bf16(
                    a[ks], b[nt][ks], acc[nt], 0, 0, 0);

        // add P1 (h@Wl) — same lane->(row,col) C mapping, bf16 frags
        const uint4* pp = (const uint4*)(P1f + ((size_t)rt * 64 + lane) * 32 + ch * 16);
        uint4 p0 = pp[0], p1 = pp[1];
        acc[0][0] += bf2f((ushort)(p0.x & 0xFFFF));
        acc[0][1] += bf2f((ushort)(p0.x >> 16));
        acc[0][2] += bf2f((ushort)(p0.y & 0xFFFF));
        acc[0][3] += bf2f((ushort)(p0.y >> 16));
        acc[1][0] += bf2f((ushort)(p0.z & 0xFFFF));
        acc[1][1] += bf2f((ushort)(p0.z >> 16));
        acc[1][2] += bf2f((ushort)(p0.w & 0xFFFF));
        acc[1][3] += bf2f((ushort)(p0.w >> 16));
        acc[2][0] += bf2f((ushort)(p1.x & 0xFFFF));
        acc[2][1] += bf2f((ushort)(p1.x >> 16));
        acc[2][2] += bf2f((ushort)(p1.y & 0xFFFF));
        acc[2][3] += bf2f((ushort)(p1.y >> 16));
        acc[3][0] += bf2f((ushort)(p1.z & 0xFFFF));
        acc[3][1] += bf2f((ushort)(p1.z >> 16));
        acc[3][2] += bf2f((ushort)(p1.w & 0xFFFF));
        acc[3][3] += bf2f((ushort)(p1.w >> 16));

        int colBase = ch * 64 + m;
        int rowBase = rt * 16 + quad * 4;
        #pragma unroll
        for (int nt = 0; nt < 4; ++nt)
            #pragma unroll
            for (int r = 0; r < 4; ++r)
                out[(size_t)(rowBase + r) * DIM + colBase + nt * 16] =
                    fmaxf(acc[nt][r], 0.f);

        // fused fixup: rows with no in-edges -> exact fp32 h@We (rare)
        unsigned long long zmask =
            __ballot(head[rt * 16 + (lane & 15)] < 0) & 0xFFFFull;
        while (zmask) {
            int row = __builtin_ctzll(zmask);
            zmask &= zmask - 1;
            int n = rt * 16 + row;
            int c0 = lane * 2;
            float s0 = 0.f, s1 = 0.f;
            for (int k = 0; k < DIM; ++k) {
                float hv = hf[(size_t)n * DIM + k];
                s0 = fmaf(hv, We[(size_t)k * DIM + c0], s0);
                s1 = fmaf(hv, We[(size_t)k * DIM + c0 + 1], s1);
            }
            out[(size_t)n * DIM + c0]     = fmaxf(s0, 0.f);
            out[(size_t)n * DIM + c0 + 1] = fmaxf(s1, 0.f);
        }
    }
}

extern "C" void kernel_launch(void* const* d_in, const int* in_sizes, int n_in,
                              void* d_out, int out_size, void* d_ws, size_t ws_size,
                              hipStream_t stream)
{
    const float* h    = (const float*)d_in[0];
    const float* norm = (const float*)d_in[1];
    const float* emb  = (const float*)d_in[2];
    const float* Wn   = (const float*)d_in[3];
    const float* Wl   = (const float*)d_in[4];
    const float* We   = (const float*)d_in[5];
    const int* src    = (const int*)d_in[6];
    const int* dst    = (const int*)d_in[7];
    const int* etype  = (const int*)d_in[8];

    const int N = in_sizes[1];
    const int E = in_sizes[6];
    const int R = in_sizes[2] / DIM;

    // ws layout (16B-aligned pieces):
    // h_bf[N*128]u16 | emb_bf[R*128]u16 | Bpack[32768]u16 | aggn_bf[N*128]u16
    // | list[E]uint2 | head[N] | P1f[N*128]u16
    char* p = (char*)d_ws;
    ushort* h_bf    = (ushort*)p;  p += (size_t)N * DIM * 2;
    ushort* emb_bf  = (ushort*)p;  p += (size_t)R * DIM * 2;
    ushort* Bpack   = (ushort*)p;  p += 2 * DIM * DIM * 2;
    ushort* aggn_bf = (ushort*)p;  p += (size_t)N * DIM * 2;
    uint2*  list    = (uint2*)p;   p += (size_t)E * 8;
    int*    head    = (int*)p;     p += ((size_t)N * 4 + 15) & ~(size_t)15;
    ushort* P1f     = (ushort*)p;

    const int nH8 = N * DIM / 8;
    const int nE8 = R * DIM / 8;
    const int initTotal = nH8 + nE8 + 32768 + N;

    init_kernel<<<dim3((initTotal + 255) / 256), dim3(256), 0, stream>>>(
        (const float4*)h, (const float4*)emb, Wn, Wl,
        (uint4*)h_bf, (uint4*)emb_bf, Bpack, head, nH8, nE8, N);

    build_kernel<<<dim3((E / 4 + 255) / 256), dim3(256), 0, stream>>>(
        (const int4*)src, (const int4*)dst, (const int4*)etype,
        head, list, E / 4, src, dst, etype, E);

    // role-split: gather blocks first, then P1 blocks (concurrent in one launch)
    const int nGroups = (N + 1) / 2;
    const int gatherBlocks = (nGroups + 15) / 16;
    const int p1Blocks = 256;
    const int nRowTiles = (N + 15) / 16;     // N=50000 -> 3125 exact
    gather_p1_kernel<<<dim3(gatherBlocks + p1Blocks), dim3(256), 0, stream>>>(
        (const uint4*)h_bf, (const uint4*)emb_bf, norm, head, list,
        (uint4*)aggn_bf, h_bf, Bpack, P1f,
        N, gatherBlocks, nRowTiles, p1Blocks * 4);

    p2_kernel<<<dim3(512), dim3(256), 0, stream>>>(
        aggn_bf, Bpack, P1f, head, h, We, (float*)d_out, nRowTiles, 1024);
}

// Round 9
// 178.293 us; speedup vs baseline: 1.3188x; 1.3188x over previous
//
#include <hip/hip_runtime.h>
#include <hip/hip_bf16.h>

// N=50000, E=600000, D=128, R=500 — fp32 inputs, bf16-tolerant check (thr 0.535).
// out = relu( (gather_sum(h[src]+emb[etype]) * norm) @ Wn + h @ (deg>0 ? Wl : We) )
// R9: revert R8's role-split regression (P1 GEMM role raised gather VGPR 36->100,
// occupancy 26->16%, gather 43->105us). Best-known R5/R6 structure + two safe
// trims: (1) head init via tiny hipMemsetAsync(0xFF); (2) init+build fused in
// one role-split kernel (both ~30 VGPR, independent, memory-bound on different
// targets). Gather stays in its own lean kernel (36 VGPR — do not touch).

#define DIM 128

typedef __attribute__((ext_vector_type(8))) short bf16x8_t;
typedef __attribute__((ext_vector_type(4))) float f32x4_t;

__device__ inline ushort f2bf(float f) {
    __hip_bfloat16 b = __float2bfloat16(f);
    return *reinterpret_cast<ushort*>(&b);
}
__device__ inline float bf2f(ushort u) {
    unsigned v = ((unsigned)u) << 16;
    return __uint_as_float(v);
}
__device__ inline uint4 cvt8(const float4& a, const float4& b) {
    uint4 o;
    o.x = f2bf(a.x) | ((unsigned)f2bf(a.y) << 16);
    o.y = f2bf(a.z) | ((unsigned)f2bf(a.w) << 16);
    o.z = f2bf(b.x) | ((unsigned)f2bf(b.y) << 16);
    o.w = f2bf(b.z) | ((unsigned)f2bf(b.w) << 16);
    return o;
}

// ---------- k1: fused init (role A) || linked-list build (role B) ----------
// Role A ranges: [0,nH8) h conv | [+nE8) emb conv | +32768 Bpack.
// Role B: list[e] = { src|etype<<17, prev head }; head[dst] = e.
// head[] pre-set to -1 by hipMemsetAsync(0xFF) before this kernel.
__global__ __launch_bounds__(256) void init_build_kernel(
    const float4* __restrict__ h4, const float4* __restrict__ emb4,
    const float* __restrict__ Wn, const float* __restrict__ Wl,
    uint4* __restrict__ h8, uint4* __restrict__ emb8,
    ushort* __restrict__ Bpack,
    const int4* __restrict__ src4, const int4* __restrict__ dst4,
    const int4* __restrict__ et4, int* __restrict__ head,
    uint2* __restrict__ list,
    const int* __restrict__ src, const int* __restrict__ dst,
    const int* __restrict__ etype,
    int nH8, int nE8, int initBlocks, int E4, int E)
{
    if ((int)blockIdx.x < initBlocks) {
        // ---- role A: conversions + B packing ----
        int i = blockIdx.x * 256 + threadIdx.x;
        if (i < nH8) {
            h8[i] = cvt8(h4[2 * i], h4[2 * i + 1]);
            return;
        }
        int j = i - nH8;
        if (j < nE8) {
            emb8[j] = cvt8(emb4[2 * j], emb4[2 * j + 1]);
            return;
        }
        j -= nE8;
        if (j < 32768) {
            // Bpack[(((nt8*8+ks8)*64+lane)*8+jj)] =
            //   W[ks8*32+(lane>>4)*8+jj][nt8*16+(lane&15)]
            // ks8 0..3 -> Wn rows; ks8 4..7 -> Wl rows. nt8 0..7 -> 128 cols.
            int jj   = j & 7;
            int lane = (j >> 3) & 63;
            int ks   = (j >> 9) & 7;
            int nt   = j >> 12;
            int k = ks * 32 + (lane >> 4) * 8 + jj;
            int n = nt * 16 + (lane & 15);
            float v = (k < DIM) ? Wn[k * DIM + n] : Wl[(k - DIM) * DIM + n];
            Bpack[j] = f2bf(v);
        }
        return;
    }

    // ---- role B: one-pass linked-list bucketing ----
    int i = ((int)blockIdx.x - initBlocks) * 256 + threadIdx.x;
    if (i < E4) {
        int4 s = src4[i], d = dst4[i], t = et4[i];
        int e = 4 * i;
        int old;
        old = atomicExch(head + d.x, e + 0);
        list[e + 0] = make_uint2((unsigned)s.x | ((unsigned)t.x << 17), (unsigned)old);
        old = atomicExch(head + d.y, e + 1);
        list[e + 1] = make_uint2((unsigned)s.y | ((unsigned)t.y << 17), (unsigned)old);
        old = atomicExch(head + d.z, e + 2);
        list[e + 2] = make_uint2((unsigned)s.z | ((unsigned)t.z << 17), (unsigned)old);
        old = atomicExch(head + d.w, e + 3);
        list[e + 3] = make_uint2((unsigned)s.w | ((unsigned)t.w << 17), (unsigned)old);
    }
    if (i == 0)
        for (int e = E4 * 4; e < E; ++e) {
            int old = atomicExch(head + dst[e], e);
            list[e] = make_uint2((unsigned)src[e] | ((unsigned)etype[e] << 17),
                                 (unsigned)old);
        }
}

// ---------- k2: bf16 gather, 2 interleaved chains per 16-lane group --------
// Lean by design: 36 VGPR, no LDS, 256 threads (R8 showed raising this
// kernel's register envelope is a 2.4x regression).
__device__ inline void addbf8(float* a, uint4 hv, uint4 rv) {
    a[0] += bf2f((ushort)(hv.x & 0xFFFF)) + bf2f((ushort)(rv.x & 0xFFFF));
    a[1] += bf2f((ushort)(hv.x >> 16))    + bf2f((ushort)(rv.x >> 16));
    a[2] += bf2f((ushort)(hv.y & 0xFFFF)) + bf2f((ushort)(rv.y & 0xFFFF));
    a[3] += bf2f((ushort)(hv.y >> 16))    + bf2f((ushort)(rv.y >> 16));
    a[4] += bf2f((ushort)(hv.z & 0xFFFF)) + bf2f((ushort)(rv.z & 0xFFFF));
    a[5] += bf2f((ushort)(hv.z >> 16))    + bf2f((ushort)(rv.z >> 16));
    a[6] += bf2f((ushort)(hv.w & 0xFFFF)) + bf2f((ushort)(rv.w & 0xFFFF));
    a[7] += bf2f((ushort)(hv.w >> 16))    + bf2f((ushort)(rv.w >> 16));
}
__device__ inline void store8(uint4* aggn8, int n, int lane, const float* a, float nm) {
    uint4 o;
    o.x = f2bf(a[0] * nm) | ((unsigned)f2bf(a[1] * nm) << 16);
    o.y = f2bf(a[2] * nm) | ((unsigned)f2bf(a[3] * nm) << 16);
    o.z = f2bf(a[4] * nm) | ((unsigned)f2bf(a[5] * nm) << 16);
    o.w = f2bf(a[6] * nm) | ((unsigned)f2bf(a[7] * nm) << 16);
    aggn8[(size_t)n * 16 + lane] = o;
}

__global__ __launch_bounds__(256) void gather_kernel(
    const uint4* __restrict__ h8,      // [N][16] bf16
    const uint4* __restrict__ emb8,    // [R][16] bf16
    const float* __restrict__ norm,
    const int* __restrict__ head,
    const uint2* __restrict__ list,
    uint4* __restrict__ aggn8,         // [N][16] bf16
    int N)
{
    int g = blockIdx.x * 16 + (threadIdx.x >> 4);   // group id
    int lane = threadIdx.x & 15;
    int n0 = 2 * g;
    int n1 = 2 * g + 1;
    if (n0 >= N) return;
    bool has1 = (n1 < N);
    int c0 = head[n0];
    int c1 = has1 ? head[n1] : -1;

    float a0[8] = {0.f, 0.f, 0.f, 0.f, 0.f, 0.f, 0.f, 0.f};
    float a1[8] = {0.f, 0.f, 0.f, 0.f, 0.f, 0.f, 0.f, 0.f};

    while ((c0 >= 0) || (c1 >= 0)) {
        bool d0 = (c0 >= 0), d1 = (c1 >= 0);
        uint2 v0, v1;
        uint4 hv0, rv0, hv1, rv1;
        if (d0) v0 = list[c0];
        if (d1) v1 = list[c1];
        if (d0) {
            hv0 = h8[(size_t)(v0.x & 0x1FFFF) * 16 + lane];
            rv0 = emb8[(size_t)(v0.x >> 17) * 16 + lane];
        }
        if (d1) {
            hv1 = h8[(size_t)(v1.x & 0x1FFFF) * 16 + lane];
            rv1 = emb8[(size_t)(v1.x >> 17) * 16 + lane];
        }
        if (d0) { addbf8(a0, hv0, rv0); c0 = (int)v0.y; }
        if (d1) { addbf8(a1, hv1, rv1); c1 = (int)v1.y; }
    }
    store8(aggn8, n0, lane, a0, norm[n0]);
    if (has1) store8(aggn8, n1, lane, a1, norm[n1]);
}

// ---------- k3: MFMA GEMM with fused deg==0 fixup --------------------------
// A = [aggn_bf | h_bf] (N x 256 bf16), B = Bpack ([Wn;Wl], frag layout).
// Wave: 64 cols (ch half), B in 128 VGPRs, streams 16-row tiles, 32 MFMA/tile.
// Epilogue: rows with head<0 (expected ~0.3 of 50000) -> exact fp32 h@We.
__global__ __launch_bounds__(256) void mfma_gemm_kernel(
    const ushort* __restrict__ aggn_bf,  // [N][128]
    const ushort* __restrict__ h_bf,     // [N][128]
    const ushort* __restrict__ Bpack,
    const int* __restrict__ head,        // [N]
    const float* __restrict__ hf,        // [N][128] fp32
    const float* __restrict__ We,        // [128][128] fp32
    float* __restrict__ out,             // [N][128]
    int nRowTiles, int halfWaves)
{
    int wave = threadIdx.x >> 6;
    int lane = threadIdx.x & 63;
    int wid  = blockIdx.x * 4 + wave;
    int ch   = wid & 1;                  // column half
    int w    = wid >> 1;
    int m    = lane & 15;
    int quad = lane >> 4;

    bf16x8_t b[4][8];
    #pragma unroll
    for (int nt = 0; nt < 4; ++nt)
        #pragma unroll
        for (int ks = 0; ks < 8; ++ks)
            b[nt][ks] = *(const bf16x8_t*)(Bpack +
                (((size_t)(ch * 4 + nt) * 8 + ks) * 64 + lane) * 8);

    for (int rt = w; rt < nRowTiles; rt += halfWaves) {
        size_t rowOff = (size_t)(rt * 16 + m) * DIM + quad * 8;
        bf16x8_t a[8];
        #pragma unroll
        for (int ks = 0; ks < 4; ++ks) {
            a[ks]     = *(const bf16x8_t*)(aggn_bf + rowOff + ks * 32);
            a[ks + 4] = *(const bf16x8_t*)(h_bf   + rowOff + ks * 32);
        }
        f32x4_t acc[4];
        #pragma unroll
        for (int nt = 0; nt < 4; ++nt) {
            acc[nt][0] = 0.f; acc[nt][1] = 0.f;
            acc[nt][2] = 0.f; acc[nt][3] = 0.f;
        }

        #pragma unroll
        for (int ks = 0; ks < 8; ++ks)
            #pragma unroll
            for (int nt = 0; nt < 4; ++nt)
                acc[nt] = __builtin_amdgcn_mfma_f32_16x16x32_bf16(
                    a[ks], b[nt][ks], acc[nt], 0, 0, 0);

        int colBase = ch * 64 + m;
        int rowBase = rt * 16 + quad * 4;
        #pragma unroll
        for (int nt = 0; nt < 4; ++nt)
            #pragma unroll
            for (int r = 0; r < 4; ++r)
                out[(size_t)(rowBase + r) * DIM + colBase + nt * 16] =
                    fmaxf(acc[nt][r], 0.f);

        // fused fixup: rows with no in-edges -> exact fp32 h@We (rare)
        unsigned long long zmask =
            __ballot(head[rt * 16 + (lane & 15)] < 0) & 0xFFFFull;
        while (zmask) {
            int row = __builtin_ctzll(zmask);
            zmask &= zmask - 1;
            int n = rt * 16 + row;
            int c0 = lane * 2;
            float s0 = 0.f, s1 = 0.f;
            for (int k = 0; k < DIM; ++k) {
                float hv = hf[(size_t)n * DIM + k];
                s0 = fmaf(hv, We[(size_t)k * DIM + c0], s0);
                s1 = fmaf(hv, We[(size_t)k * DIM + c0 + 1], s1);
            }
            out[(size_t)n * DIM + c0]     = fmaxf(s0, 0.f);
            out[(size_t)n * DIM + c0 + 1] = fmaxf(s1, 0.f);
        }
    }
}

extern "C" void kernel_launch(void* const* d_in, const int* in_sizes, int n_in,
                              void* d_out, int out_size, void* d_ws, size_t ws_size,
                              hipStream_t stream)
{
    const float* h    = (const float*)d_in[0];
    const float* norm = (const float*)d_in[1];
    const float* emb  = (const float*)d_in[2];
    const float* Wn   = (const float*)d_in[3];
    const float* Wl   = (const float*)d_in[4];
    const float* We   = (const float*)d_in[5];
    const int* src    = (const int*)d_in[6];
    const int* dst    = (const int*)d_in[7];
    const int* etype  = (const int*)d_in[8];

    const int N = in_sizes[1];
    const int E = in_sizes[6];
    const int R = in_sizes[2] / DIM;

    // ws layout (16B-aligned pieces):
    // h_bf[N*128]u16 | emb_bf[R*128]u16 | Bpack[32768]u16 | aggn_bf[N*128]u16
    // | list[E]uint2 | head[N]
    char* p = (char*)d_ws;
    ushort* h_bf    = (ushort*)p;  p += (size_t)N * DIM * 2;
    ushort* emb_bf  = (ushort*)p;  p += (size_t)R * DIM * 2;
    ushort* Bpack   = (ushort*)p;  p += 2 * DIM * DIM * 2;
    ushort* aggn_bf = (ushort*)p;  p += (size_t)N * DIM * 2;
    uint2*  list    = (uint2*)p;   p += (size_t)E * 8;
    int*    head    = (int*)p;

    // head[] = -1 via byte pattern 0xFF (200 KB — negligible)
    hipMemsetAsync(head, 0xFF, (size_t)N * sizeof(int), stream);

    const int nH8 = N * DIM / 8;
    const int nE8 = R * DIM / 8;
    const int initTotal = nH8 + nE8 + 32768;
    const int initBlocks = (initTotal + 255) / 256;
    const int E4 = E / 4;
    const int buildBlocks = (E4 + 255) / 256;

    init_build_kernel<<<dim3(initBlocks + buildBlocks), dim3(256), 0, stream>>>(
        (const float4*)h, (const float4*)emb, Wn, Wl,
        (uint4*)h_bf, (uint4*)emb_bf, Bpack,
        (const int4*)src, (const int4*)dst, (const int4*)etype,
        head, list, src, dst, etype,
        nH8, nE8, initBlocks, E4, E);

    const int nGroups = (N + 1) / 2;
    gather_kernel<<<dim3((nGroups + 15) / 16), dim3(256), 0, stream>>>(
        (const uint4*)h_bf, (const uint4*)emb_bf, norm, head, list,
        (uint4*)aggn_bf, N);

    const int nRowTiles = (N + 15) / 16;     // N=50000 -> 3125 exact
    mfma_gemm_kernel<<<dim3(512), dim3(256), 0, stream>>>(
        aggn_bf, h_bf, Bpack, head, h, We, (float*)d_out, nRowTiles, 1024);
}

// Round 10
// 178.082 us; speedup vs baseline: 1.3204x; 1.0012x over previous
//
#include <hip/hip_runtime.h>
#include <hip/hip_bf16.h>

// N=50000, E=600000, D=128, R=500 — fp32 inputs, bf16-tolerant check (thr 0.535).
// out = relu( (gather_sum(h[src]+emb[etype]) * norm) @ Wn + h @ (deg>0 ? Wl : We) )
// R10: gather inner-loop VALU cut — bf16 unpack via single shl/and to fp32
// bit-pattern (was and+shl+shr chains) + float2 accumulators for packed
// v_pk_add_f32. Same algorithm, same resource envelope (36 VGPR, no LDS).
// Gather history: R6 2x-MLP neutral, R7 LDS/occupancy hurt, R8 VGPR hurt ->
// VMEM+VALU issue-bound; this attacks the VALU half (~28% busy).

#define DIM 128

typedef __attribute__((ext_vector_type(8))) short bf16x8_t;
typedef __attribute__((ext_vector_type(4))) float f32x4_t;

__device__ inline ushort f2bf(float f) {
    __hip_bfloat16 b = __float2bfloat16(f);
    return *reinterpret_cast<ushort*>(&b);
}
__device__ inline float bf2f(ushort u) {
    unsigned v = ((unsigned)u) << 16;
    return __uint_as_float(v);
}
__device__ inline uint4 cvt8(const float4& a, const float4& b) {
    uint4 o;
    o.x = f2bf(a.x) | ((unsigned)f2bf(a.y) << 16);
    o.y = f2bf(a.z) | ((unsigned)f2bf(a.w) << 16);
    o.z = f2bf(b.x) | ((unsigned)f2bf(b.y) << 16);
    o.w = f2bf(b.z) | ((unsigned)f2bf(b.w) << 16);
    return o;
}

// ---------- k1: fused init (role A) || linked-list build (role B) ----------
// Role A ranges: [0,nH8) h conv | [+nE8) emb conv | +32768 Bpack.
// Role B: list[e] = { src|etype<<17, prev head }; head[dst] = e.
// head[] pre-set to -1 by hipMemsetAsync(0xFF) before this kernel.
__global__ __launch_bounds__(256) void init_build_kernel(
    const float4* __restrict__ h4, const float4* __restrict__ emb4,
    const float* __restrict__ Wn, const float* __restrict__ Wl,
    uint4* __restrict__ h8, uint4* __restrict__ emb8,
    ushort* __restrict__ Bpack,
    const int4* __restrict__ src4, const int4* __restrict__ dst4,
    const int4* __restrict__ et4, int* __restrict__ head,
    uint2* __restrict__ list,
    const int* __restrict__ src, const int* __restrict__ dst,
    const int* __restrict__ etype,
    int nH8, int nE8, int initBlocks, int E4, int E)
{
    if ((int)blockIdx.x < initBlocks) {
        // ---- role A: conversions + B packing ----
        int i = blockIdx.x * 256 + threadIdx.x;
        if (i < nH8) {
            h8[i] = cvt8(h4[2 * i], h4[2 * i + 1]);
            return;
        }
        int j = i - nH8;
        if (j < nE8) {
            emb8[j] = cvt8(emb4[2 * j], emb4[2 * j + 1]);
            return;
        }
        j -= nE8;
        if (j < 32768) {
            // Bpack[(((nt8*8+ks8)*64+lane)*8+jj)] =
            //   W[ks8*32+(lane>>4)*8+jj][nt8*16+(lane&15)]
            // ks8 0..3 -> Wn rows; ks8 4..7 -> Wl rows. nt8 0..7 -> 128 cols.
            int jj   = j & 7;
            int lane = (j >> 3) & 63;
            int ks   = (j >> 9) & 7;
            int nt   = j >> 12;
            int k = ks * 32 + (lane >> 4) * 8 + jj;
            int n = nt * 16 + (lane & 15);
            float v = (k < DIM) ? Wn[k * DIM + n] : Wl[(k - DIM) * DIM + n];
            Bpack[j] = f2bf(v);
        }
        return;
    }

    // ---- role B: one-pass linked-list bucketing ----
    int i = ((int)blockIdx.x - initBlocks) * 256 + threadIdx.x;
    if (i < E4) {
        int4 s = src4[i], d = dst4[i], t = et4[i];
        int e = 4 * i;
        int old;
        old = atomicExch(head + d.x, e + 0);
        list[e + 0] = make_uint2((unsigned)s.x | ((unsigned)t.x << 17), (unsigned)old);
        old = atomicExch(head + d.y, e + 1);
        list[e + 1] = make_uint2((unsigned)s.y | ((unsigned)t.y << 17), (unsigned)old);
        old = atomicExch(head + d.z, e + 2);
        list[e + 2] = make_uint2((unsigned)s.z | ((unsigned)t.z << 17), (unsigned)old);
        old = atomicExch(head + d.w, e + 3);
        list[e + 3] = make_uint2((unsigned)s.w | ((unsigned)t.w << 17), (unsigned)old);
    }
    if (i == 0)
        for (int e = E4 * 4; e < E; ++e) {
            int old = atomicExch(head + dst[e], e);
            list[e] = make_uint2((unsigned)src[e] | ((unsigned)etype[e] << 17),
                                 (unsigned)old);
        }
}

// ---------- k2: bf16 gather, 2 interleaved chains per 16-lane group --------
// Lean: 36 VGPR, no LDS, 256 threads. Unpack = 1 VALU op per bf16 (shl or
// and to fp32 bit pattern); float2 accumulators for packed v_pk_add_f32.
__device__ inline void addw(float2& a, unsigned hw, unsigned rw) {
    // element 2j   = low bf16  -> fp32 via <<16
    // element 2j+1 = high bf16 -> fp32 via & 0xFFFF0000
    float2 t, u;
    t.x = __uint_as_float(hw << 16);
    t.y = __uint_as_float(hw & 0xFFFF0000u);
    u.x = __uint_as_float(rw << 16);
    u.y = __uint_as_float(rw & 0xFFFF0000u);
    a.x += t.x + u.x;
    a.y += t.y + u.y;
}
__device__ inline void addbf8(float2* a, uint4 hv, uint4 rv) {
    addw(a[0], hv.x, rv.x);
    addw(a[1], hv.y, rv.y);
    addw(a[2], hv.z, rv.z);
    addw(a[3], hv.w, rv.w);
}
__device__ inline void store8(uint4* aggn8, int n, int lane,
                              const float2* a, float nm) {
    uint4 o;
    o.x = f2bf(a[0].x * nm) | ((unsigned)f2bf(a[0].y * nm) << 16);
    o.y = f2bf(a[1].x * nm) | ((unsigned)f2bf(a[1].y * nm) << 16);
    o.z = f2bf(a[2].x * nm) | ((unsigned)f2bf(a[2].y * nm) << 16);
    o.w = f2bf(a[3].x * nm) | ((unsigned)f2bf(a[3].y * nm) << 16);
    aggn8[(size_t)n * 16 + lane] = o;
}

__global__ __launch_bounds__(256) void gather_kernel(
    const uint4* __restrict__ h8,      // [N][16] bf16
    const uint4* __restrict__ emb8,    // [R][16] bf16
    const float* __restrict__ norm,
    const int* __restrict__ head,
    const uint2* __restrict__ list,
    uint4* __restrict__ aggn8,         // [N][16] bf16
    int N)
{
    int g = blockIdx.x * 16 + (threadIdx.x >> 4);   // group id
    int lane = threadIdx.x & 15;
    int n0 = 2 * g;
    int n1 = 2 * g + 1;
    if (n0 >= N) return;
    bool has1 = (n1 < N);
    int c0 = head[n0];
    int c1 = has1 ? head[n1] : -1;

    float2 a0[4] = {{0.f,0.f},{0.f,0.f},{0.f,0.f},{0.f,0.f}};
    float2 a1[4] = {{0.f,0.f},{0.f,0.f},{0.f,0.f},{0.f,0.f}};

    while ((c0 >= 0) || (c1 >= 0)) {
        bool d0 = (c0 >= 0), d1 = (c1 >= 0);
        uint2 v0, v1;
        uint4 hv0, rv0, hv1, rv1;
        if (d0) v0 = list[c0];
        if (d1) v1 = list[c1];
        if (d0) {
            hv0 = h8[(size_t)(v0.x & 0x1FFFF) * 16 + lane];
            rv0 = emb8[(size_t)(v0.x >> 17) * 16 + lane];
        }
        if (d1) {
            hv1 = h8[(size_t)(v1.x & 0x1FFFF) * 16 + lane];
            rv1 = emb8[(size_t)(v1.x >> 17) * 16 + lane];
        }
        if (d0) { addbf8(a0, hv0, rv0); c0 = (int)v0.y; }
        if (d1) { addbf8(a1, hv1, rv1); c1 = (int)v1.y; }
    }
    store8(aggn8, n0, lane, a0, norm[n0]);
    if (has1) store8(aggn8, n1, lane, a1, norm[n1]);
}

// ---------- k3: MFMA GEMM with fused deg==0 fixup --------------------------
// A = [aggn_bf | h_bf] (N x 256 bf16), B = Bpack ([Wn;Wl], frag layout).
// Wave: 64 cols (ch half), B in 128 VGPRs, streams 16-row tiles, 32 MFMA/tile.
// Epilogue: rows with head<0 (expected ~0.3 of 50000) -> exact fp32 h@We.
__global__ __launch_bounds__(256) void mfma_gemm_kernel(
    const ushort* __restrict__ aggn_bf,  // [N][128]
    const ushort* __restrict__ h_bf,     // [N][128]
    const ushort* __restrict__ Bpack,
    const int* __restrict__ head,        // [N]
    const float* __restrict__ hf,        // [N][128] fp32
    const float* __restrict__ We,        // [128][128] fp32
    float* __restrict__ out,             // [N][128]
    int nRowTiles, int halfWaves)
{
    int wave = threadIdx.x >> 6;
    int lane = threadIdx.x & 63;
    int wid  = blockIdx.x * 4 + wave;
    int ch   = wid & 1;                  // column half
    int w    = wid >> 1;
    int m    = lane & 15;
    int quad = lane >> 4;

    bf16x8_t b[4][8];
    #pragma unroll
    for (int nt = 0; nt < 4; ++nt)
        #pragma unroll
        for (int ks = 0; ks < 8; ++ks)
            b[nt][ks] = *(const bf16x8_t*)(Bpack +
                (((size_t)(ch * 4 + nt) * 8 + ks) * 64 + lane) * 8);

    for (int rt = w; rt < nRowTiles; rt += halfWaves) {
        size_t rowOff = (size_t)(rt * 16 + m) * DIM + quad * 8;
        bf16x8_t a[8];
        #pragma unroll
        for (int ks = 0; ks < 4; ++ks) {
            a[ks]     = *(const bf16x8_t*)(aggn_bf + rowOff + ks * 32);
            a[ks + 4] = *(const bf16x8_t*)(h_bf   + rowOff + ks * 32);
        }
        f32x4_t acc[4];
        #pragma unroll
        for (int nt = 0; nt < 4; ++nt) {
            acc[nt][0] = 0.f; acc[nt][1] = 0.f;
            acc[nt][2] = 0.f; acc[nt][3] = 0.f;
        }

        #pragma unroll
        for (int ks = 0; ks < 8; ++ks)
            #pragma unroll
            for (int nt = 0; nt < 4; ++nt)
                acc[nt] = __builtin_amdgcn_mfma_f32_16x16x32_bf16(
                    a[ks], b[nt][ks], acc[nt], 0, 0, 0);

        int colBase = ch * 64 + m;
        int rowBase = rt * 16 + quad * 4;
        #pragma unroll
        for (int nt = 0; nt < 4; ++nt)
            #pragma unroll
            for (int r = 0; r < 4; ++r)
                out[(size_t)(rowBase + r) * DIM + colBase + nt * 16] =
                    fmaxf(acc[nt][r], 0.f);

        // fused fixup: rows with no in-edges -> exact fp32 h@We (rare)
        unsigned long long zmask =
            __ballot(head[rt * 16 + (lane & 15)] < 0) & 0xFFFFull;
        while (zmask) {
            int row = __builtin_ctzll(zmask);
            zmask &= zmask - 1;
            int n = rt * 16 + row;
            int c0 = lane * 2;
            float s0 = 0.f, s1 = 0.f;
            for (int k = 0; k < DIM; ++k) {
                float hv = hf[(size_t)n * DIM + k];
                s0 = fmaf(hv, We[(size_t)k * DIM + c0], s0);
                s1 = fmaf(hv, We[(size_t)k * DIM + c0 + 1], s1);
            }
            out[(size_t)n * DIM + c0]     = fmaxf(s0, 0.f);
            out[(size_t)n * DIM + c0 + 1] = fmaxf(s1, 0.f);
        }
    }
}

extern "C" void kernel_launch(void* const* d_in, const int* in_sizes, int n_in,
                              void* d_out, int out_size, void* d_ws, size_t ws_size,
                              hipStream_t stream)
{
    const float* h    = (const float*)d_in[0];
    const float* norm = (const float*)d_in[1];
    const float* emb  = (const float*)d_in[2];
    const float* Wn   = (const float*)d_in[3];
    const float* Wl   = (const float*)d_in[4];
    const float* We   = (const float*)d_in[5];
    const int* src    = (const int*)d_in[6];
    const int* dst    = (const int*)d_in[7];
    const int* etype  = (const int*)d_in[8];

    const int N = in_sizes[1];
    const int E = in_sizes[6];
    const int R = in_sizes[2] / DIM;

    // ws layout (16B-aligned pieces):
    // h_bf[N*128]u16 | emb_bf[R*128]u16 | Bpack[32768]u16 | aggn_bf[N*128]u16
    // | list[E]uint2 | head[N]
    char* p = (char*)d_ws;
    ushort* h_bf    = (ushort*)p;  p += (size_t)N * DIM * 2;
    ushort* emb_bf  = (ushort*)p;  p += (size_t)R * DIM * 2;
    ushort* Bpack   = (ushort*)p;  p += 2 * DIM * DIM * 2;
    ushort* aggn_bf = (ushort*)p;  p += (size_t)N * DIM * 2;
    uint2*  list    = (uint2*)p;   p += (size_t)E * 8;
    int*    head    = (int*)p;

    // head[] = -1 via byte pattern 0xFF (200 KB — negligible)
    hipMemsetAsync(head, 0xFF, (size_t)N * sizeof(int), stream);

    const int nH8 = N * DIM / 8;
    const int nE8 = R * DIM / 8;
    const int initTotal = nH8 + nE8 + 32768;
    const int initBlocks = (initTotal + 255) / 256;
    const int E4 = E / 4;
    const int buildBlocks = (E4 + 255) / 256;

    init_build_kernel<<<dim3(initBlocks + buildBlocks), dim3(256), 0, stream>>>(
        (const float4*)h, (const float4*)emb, Wn, Wl,
        (uint4*)h_bf, (uint4*)emb_bf, Bpack,
        (const int4*)src, (const int4*)dst, (const int4*)etype,
        head, list, src, dst, etype,
        nH8, nE8, initBlocks, E4, E);

    const int nGroups = (N + 1) / 2;
    gather_kernel<<<dim3((nGroups + 15) / 16), dim3(256), 0, stream>>>(
        (const uint4*)h_bf, (const uint4*)emb_bf, norm, head, list,
        (uint4*)aggn_bf, N);

    const int nRowTiles = (N + 15) / 16;     // N=50000 -> 3125 exact
    mfma_gemm_kernel<<<dim3(512), dim3(256), 0, stream>>>(
        aggn_bf, h_bf, Bpack, head, h, We, (float*)d_out, nRowTiles, 1024);
}